// Round 5
// baseline (1412.164 us; speedup 1.0000x reference)
//
#include <hip/hip_runtime.h>
#include <hip/hip_bf16.h>

#define VOCAB 32000
#define HID   256
#define BATCH 32
#define SEQ   128
#define MROWS (BATCH * SEQ)  // 4096
#define NCB   250            // VOCAB / 128 column blocks

typedef _Float16 f16;
typedef _Float16 f16x4 __attribute__((ext_vector_type(4)));
typedef _Float16 f16x8 __attribute__((ext_vector_type(8)));
typedef float    f32x4 __attribute__((ext_vector_type(4)));

#define GLOAD_LDS16(gptr, lptr)                                                       \
  __builtin_amdgcn_global_load_lds(                                                   \
      (const __attribute__((address_space(1))) unsigned int*)(gptr),                  \
      (__attribute__((address_space(3))) unsigned int*)(lptr), 16, 0, 0)

// ---------------------------------------------------------------------------
// 1) prep: blocks [0,8000): emb fp32->fp16 cast; blocks [8000,8256):
//    X1 = (masked emb-gather) @ Wx1^T + b1 (16-row tiles).  Block 8000 also
//    zeroes the gemm-pass-1 completion counters.
// ---------------------------------------------------------------------------
__global__ __launch_bounds__(256) void prep_kernel(
    const float* __restrict__ emb, f16* __restrict__ embh,
    const int* __restrict__ tokens, const int* __restrict__ lengths,
    const float* __restrict__ W, const float* __restrict__ bias,
    float* __restrict__ Out, unsigned* __restrict__ cnt) {
  const int blk = blockIdx.x;
  const int tid = threadIdx.x;
  if (blk < 8000) {  // cast: 8000*256 float4 = VOCAB*HID/4 exactly
    int idx = blk * 256 + tid;
    float4 v = ((const float4*)emb)[idx];
    f16x4 o = {(f16)v.x, (f16)v.y, (f16)v.z, (f16)v.w};
    ((f16x4*)embh)[idx] = o;
    return;
  }
  if (blk == 8000 && tid < 32) cnt[tid] = 0u;  // reset pass-1 counters
  __shared__ float sIn[16 * 256];
  const int rb = (blk - 8000) * 16;
  float4* s4 = (float4*)sIn;
#pragma unroll
  for (int q = 0; q < 4; ++q) {
    int f = tid + q * 256;  // float4 index within 16x256 tile
    int row = f >> 6;       // 0..15
    int c4 = f & 63;
    int gr = rb + row;      // global row = b*SEQ + t
    int bb = gr >> 7, t = gr & 127;
    float4 v = make_float4(0.f, 0.f, 0.f, 0.f);
    if (t < lengths[bb]) {
      int tok = tokens[gr];
      v = ((const float4*)(emb + (size_t)tok * 256))[c4];
    }
    s4[f] = v;
  }
  __syncthreads();
  const int i = tid;
  float acc[16];
#pragma unroll
  for (int r = 0; r < 16; ++r) acc[r] = 0.f;
  const float4* w4 = (const float4*)(W + (size_t)i * 256);
#pragma unroll 4
  for (int j = 0; j < 64; ++j) {
    float4 wv = w4[j];
#pragma unroll
    for (int r = 0; r < 16; ++r) {
      float4 sv = ((const float4*)(sIn + r * 256))[j];
      acc[r] += sv.x * wv.x + sv.y * wv.y + sv.z * wv.z + sv.w * wv.w;
    }
  }
  float bi = bias[i];
#pragma unroll
  for (int r = 0; r < 16; ++r) Out[(size_t)(rb + r) * 256 + i] = acc[r] + bi;
}

// ---------------------------------------------------------------------------
// 2) X = In @ W^T + bias  (layer-2 input prep, linear In)
// ---------------------------------------------------------------------------
__global__ __launch_bounds__(256) void xprep_kernel(
    const float* __restrict__ In, const float* __restrict__ W,
    const float* __restrict__ bias, float* __restrict__ Out) {
  __shared__ float sIn[16 * 256];
  int tid = threadIdx.x;
  int rb = blockIdx.x * 16;
  const float4* g = (const float4*)(In + (size_t)rb * 256);
  float4* s4 = (float4*)sIn;
#pragma unroll
  for (int q = 0; q < 4; ++q) s4[tid + q * 256] = g[tid + q * 256];
  __syncthreads();
  int i = tid;
  float acc[16];
#pragma unroll
  for (int r = 0; r < 16; ++r) acc[r] = 0.f;
  const float4* w4 = (const float4*)(W + (size_t)i * 256);
#pragma unroll 4
  for (int j = 0; j < 64; ++j) {
    float4 wv = w4[j];
#pragma unroll
    for (int r = 0; r < 16; ++r) {
      float4 sv = ((const float4*)(sIn + r * 256))[j];
      acc[r] += sv.x * wv.x + sv.y * wv.y + sv.z * wv.z + sv.w * wv.w;
    }
  }
  float bi = bias[i];
#pragma unroll
  for (int r = 0; r < 16; ++r) Out[(size_t)(rb + r) * 256 + i] = acc[r] + bi;
}

// ---------------------------------------------------------------------------
// 3) recurrence: h_t = tanh(X_t + h_{t-1} @ Wh^T); wave-level K-split,
//    one barrier per step, fast tanh, optional f16 mirror (h2 cast fused).
// ---------------------------------------------------------------------------
__global__ __launch_bounds__(512) void rnn_kernel(
    const float* __restrict__ X, const float* __restrict__ Wh,
    const int* __restrict__ lengths, float* __restrict__ Hout,
    f16* __restrict__ H16) {
  int b = blockIdx.x;
  int tid = threadIdx.x;
  int wave = tid >> 6;
  int lane = tid & 63;
  int o = wave * 32 + (lane & 31);  // output index this lane serves
  int kh = lane >> 5;               // K-half (0/1)
  float w[128];
  {
    const float4* wr = (const float4*)(Wh + (size_t)o * 256 + kh * 128);
#pragma unroll
    for (int q = 0; q < 32; ++q) {
      float4 v = wr[q];
      w[4 * q + 0] = v.x; w[4 * q + 1] = v.y;
      w[4 * q + 2] = v.z; w[4 * q + 3] = v.w;
    }
  }
  __shared__ float sh[2][256];
  if (tid < 256) sh[0][tid] = 0.f;
  int len = lengths[b];
  const float* Xb = X + (size_t)b * SEQ * HID;
  float* Hb = Hout + (size_t)b * SEQ * HID;
  f16* H16b = H16 + (size_t)b * SEQ * HID;  // only deref'd if H16 != nullptr
  __syncthreads();
  float xnext = (kh == 0) ? Xb[o] : 0.f;
  for (int t = 0; t < SEQ; ++t) {
    const int cur = t & 1;
    float a0 = 0.f, a1 = 0.f, a2 = 0.f, a3 = 0.f;
    const float4* hp = (const float4*)(sh[cur] + kh * 128);
#pragma unroll
    for (int q = 0; q < 32; ++q) {
      float4 hv = hp[q];
      a0 += hv.x * w[4 * q + 0];
      a1 += hv.y * w[4 * q + 1];
      a2 += hv.z * w[4 * q + 2];
      a3 += hv.w * w[4 * q + 3];
    }
    float acc = (a0 + a1) + (a2 + a3);
    acc += __shfl_xor(acc, 32, 64);  // combine the two K-halves
    if (kh == 0) {
      float z = xnext + acc;
      float e = __expf(2.f * z);           // fast tanh: 1 - 2/(e^{2z}+1)
      float h = 1.f - 2.f / (e + 1.f);
      float hm = (t < len) ? h : 0.f;
      Hb[(size_t)t * HID + o] = hm;        // masked output
      if (H16) H16b[(size_t)t * HID + o] = (f16)hm;
      sh[cur ^ 1][o] = h;                  // unmasked carry
      if (t + 1 < SEQ) xnext = Xb[(size_t)(t + 1) * HID + o];
    }
    __syncthreads();
  }
}

// ---------------------------------------------------------------------------
// 4) Two-pass fused GEMM+softmax, double-buffered prefetch K-loop.
//    Pass 1: per-block partials -> PM/PL, then last-block-done (device-scope
//      atomic + threadfence) folds the 250-partial combine in-kernel,
//      writing Mrow/Inv (removes the separate combine dispatch).
//    Pass 2: recompute + exp/scale/mask, nontemporal probs stores.
// ---------------------------------------------------------------------------
template <int WRITE_PROBS>
__global__ __launch_bounds__(256) void gemm_kernel(
    const f16* __restrict__ A,   // [4096][256] masked h2
    const f16* __restrict__ Bm,  // [32000][256] emb
    float* __restrict__ C,       // [4096][32000] probs (pass 2 only)
    float* __restrict__ PM,      // [4096][250] partial row max (pass 1)
    float* __restrict__ PL,      // [4096][250] partial sum exp (pass 1)
    float* __restrict__ Mrow,    // [4096] row max (written p1 tail, read p2)
    float* __restrict__ Inv,     // [4096] 1/denom (written p1 tail, read p2)
    const int* __restrict__ lengths,
    unsigned* __restrict__ cnt) {  // [32] pass-1 completion counters
  __shared__ __align__(16) f16 sAbuf[2][128 * 64];  // 32 KB
  __shared__ __align__(16) f16 sBbuf[2][128 * 64];  // 32 KB  (total = 64 KB)
  __shared__ unsigned sLast;
  const int tid = threadIdx.x;
  const int wave = tid >> 6;
  const int lane = tid & 63;

  // XCD-chunked remap (8000 blocks, 1000 per XCD; round-robin dispatch)
  const int flat = blockIdx.x + 32 * blockIdx.y;
  const int work = (flat & 7) * 1000 + (flat >> 3);
  const int bx = work & 31;   // row-block == batch element
  const int by = work >> 5;   // col-block
  const int row0 = bx * 128;
  const int col0 = by * 128;

  const int len = lengths[bx];         // block-uniform
  const int lenc = (len + 15) & ~15;   // rows needed, frag-rounded

  f32x4 acc[4][4];
#pragma unroll
  for (int a = 0; a < 4; ++a)
#pragma unroll
    for (int b = 0; b < 4; ++b) acc[a][b] = (f32x4){0.f, 0.f, 0.f, 0.f};

  const int lr = lane >> 3;  // row within 8-row group
  const int ls = lane & 7;   // LDS 16B slot within row
  const int wm = wave & 1, wn = wave >> 1;

#define STAGE(buf, koo)                                                        \
  {                                                                            \
    _Pragma("unroll") for (int ii = 0; ii < 4; ++ii) {                         \
      int ar = wave * 32 + ii * 8;                                             \
      int r = ar + lr;                                                         \
      int c = ls ^ (r & 7);                                                    \
      if (ar < lenc) {                                                         \
        const f16* ga = A + (size_t)(row0 + r) * 256 + (koo) * 64 + c * 8;     \
        GLOAD_LDS16(ga, sAbuf[buf] + ar * 64);                                 \
      }                                                                        \
      const f16* gb = Bm + (size_t)(col0 + r) * 256 + (koo) * 64 + c * 8;      \
      GLOAD_LDS16(gb, sBbuf[buf] + ar * 64);                                   \
    }                                                                          \
  }

  STAGE(0, 0);
  __syncthreads();  // prologue drain (implicit vmcnt(0))

#pragma unroll
  for (int ko = 0; ko < 4; ++ko) {
    const int cur = ko & 1;
    if (ko < 3) STAGE(cur ^ 1, ko + 1);  // prefetch overlaps compute below
#pragma unroll
    for (int kk = 0; kk < 2; ++kk) {
      const int cA = kk * 4 + (lane >> 4);
      f16x8 bf[4];
#pragma unroll
      for (int f = 0; f < 4; ++f) {
        int n = wn * 64 + f * 16 + (lane & 15);
        bf[f] = *(const f16x8*)(sBbuf[cur] + n * 64 + (cA ^ (n & 7)) * 8);
      }
#pragma unroll
      for (int fm = 0; fm < 4; ++fm) {
        const int g = fm * 2 + wm;        // interleaved row-frag index
        if (g * 16 < len) {               // wave-uniform guard
          int m = g * 16 + (lane & 15);
          f16x8 af = *(const f16x8*)(sAbuf[cur] + m * 64 + (cA ^ (m & 7)) * 8);
#pragma unroll
          for (int fn = 0; fn < 4; ++fn)
            acc[fm][fn] = __builtin_amdgcn_mfma_f32_16x16x32_f16(
                af, bf[fn], acc[fm][fn], 0, 0, 0);
        }
      }
    }
    __syncthreads();  // next buffer ready + old buffer readers done
  }
#undef STAGE

  const int lq = lane >> 4;
  const int lc = lane & 15;

  if (WRITE_PROBS) {
    // --- pass 2: probs = exp(acc - m) * inv, masked rows -> 0 ---
    // C/D layout: col=lane&15, row=(lane>>4)*4+reg.  Nontemporal stores.
    float* sM = (float*)sAbuf;  // staging buffers dead after final barrier
    float* sI = sM + 128;
    if (tid < 128) {
      sM[tid] = Mrow[row0 + tid];
      sI[tid] = Inv[row0 + tid];
    }
    __syncthreads();
#pragma unroll
    for (int fm = 0; fm < 4; ++fm)
#pragma unroll
      for (int fn = 0; fn < 4; ++fn)
#pragma unroll
        for (int rr = 0; rr < 4; ++rr) {
          int t = (fm * 2 + wm) * 16 + lq * 4 + rr;  // t within batch
          int col = col0 + wn * 64 + fn * 16 + lc;
          float v =
              (t < len) ? __expf(acc[fm][fn][rr] - sM[t]) * sI[t] : 0.f;
          __builtin_nontemporal_store(v, &C[(size_t)(row0 + t) * VOCAB + col]);
        }
  } else {
    // --- pass 1: per-block online-softmax partials; reuse staging LDS ---
    float* rm = (float*)sAbuf;     // [2][128]  per-wn per-row max
    float* rs = rm + 256;          // [2][128]  per-wn per-row sum exp
#pragma unroll
    for (int fm = 0; fm < 4; ++fm) {
      const int g = fm * 2 + wm;
      const bool active = (g * 16 < len);  // wave-uniform
#pragma unroll
      for (int rr = 0; rr < 4; ++rr) {
        int r = g * 16 + lq * 4 + rr;
        if (active) {
          float mx = fmaxf(fmaxf(acc[fm][0][rr], acc[fm][1][rr]),
                           fmaxf(acc[fm][2][rr], acc[fm][3][rr]));
#pragma unroll
          for (int off = 1; off < 16; off <<= 1)
            mx = fmaxf(mx, __shfl_xor(mx, off, 64));
          float sum = __expf(acc[fm][0][rr] - mx) +
                      __expf(acc[fm][1][rr] - mx) +
                      __expf(acc[fm][2][rr] - mx) +
                      __expf(acc[fm][3][rr] - mx);
#pragma unroll
          for (int off = 1; off < 16; off <<= 1)
            sum += __shfl_xor(sum, off, 64);
          if (lc == 0) {
            rm[wn * 128 + r] = mx;
            rs[wn * 128 + r] = sum;
          }
        } else if (lc == 0) {  // padded rows: benign partials (unused)
          rm[wn * 128 + r] = 0.f;
          rs[wn * 128 + r] = 0.f;
        }
      }
    }
    __syncthreads();
    if (tid < 128) {
      float m0 = rm[tid], m1 = rm[128 + tid];
      float M = fmaxf(m0, m1);
      float L = rs[tid] * __expf(m0 - M) + rs[128 + tid] * __expf(m1 - M);
      PM[(size_t)(row0 + tid) * NCB + by] = M;
      PL[(size_t)(row0 + tid) * NCB + by] = L;
    }
    // --- last-block-done: fold the 250-partial combine in-kernel ---
    __syncthreads();  // all PM/PL stores issued
    if (tid == 0) {
      __threadfence();  // release our PM/PL stores device-wide
      unsigned old = atomicAdd(&cnt[bx], 1u);  // device-scope by default
      sLast = (old == NCB - 1) ? 1u : 0u;
    }
    __syncthreads();
    if (sLast) {
      __threadfence();  // acquire: other blocks' PM/PL now visible
      int r = tid >> 1, h = tid & 1;  // 256 threads -> 128 rows x 2 halves
      const float* pm = PM + (size_t)(row0 + r) * NCB + h * 125;
      const float* pl = PL + (size_t)(row0 + r) * NCB + h * 125;
      float M = -3.4e38f;
      for (int k = 0; k < 125; ++k) M = fmaxf(M, pm[k]);
      float L = 0.f;
      for (int k = 0; k < 125; ++k) L += pl[k] * __expf(pm[k] - M);
      // pair lanes (2r, 2r+1) are adjacent in the same wave
      float Mo = fmaxf(M, __shfl_xor(M, 1, 64));
      float Lo = L * __expf(M - Mo);
      Lo += __shfl_xor(Lo, 1, 64);
      if (h == 0) {
        Mrow[row0 + r] = Mo;
        Inv[row0 + r] = 1.f / Lo;
      }
    }
  }
}

// ---------------------------------------------------------------------------
extern "C" void kernel_launch(void* const* d_in, const int* in_sizes, int n_in,
                              void* d_out, int out_size, void* d_ws,
                              size_t ws_size, hipStream_t stream) {
  const int* tokens = (const int*)d_in[0];
  const int* lengths = (const int*)d_in[1];
  const float* emb = (const float*)d_in[2];
  const float* Wx1 = (const float*)d_in[3];
  const float* Wh1 = (const float*)d_in[4];
  const float* b1 = (const float*)d_in[5];
  const float* Wx2 = (const float*)d_in[6];
  const float* Wh2 = (const float*)d_in[7];
  const float* b2 = (const float*)d_in[8];

  float* probs = (float*)d_out;
  float* h2out = probs + (size_t)MROWS * VOCAB;  // [4096][256] masked h2

  float* ws = (float*)d_ws;
  float* X = ws + 1048576;                     // 1,048,576 f (reused layer 2)
  float* h1 = ws + 2097152;                    // 1,048,576 f
  f16* embh = (f16*)(ws + 3145728);            // 8,192,000 halfs = 4,096,000 f
  f16* h2h = (f16*)(ws + 3145728 + 4096000);   // 1,048,576 halfs = 524,288 f
  float* PM = ws + 7766016;                    // 1,024,000 f
  float* PL = ws + 8790016;                    // 1,024,000 f
  float* Mrow = ws + 9814016;                  // 4096 f
  float* Inv = ws + 9818112;                   // 4096 f
  unsigned* cnt = (unsigned*)(ws + 9822208);   // 32 u32 pass-1 counters

  // 1: emb cast (blocks 0..7999) + gather-xprep1 (8000..8255) + cnt reset
  prep_kernel<<<8256, 256, 0, stream>>>(emb, embh, tokens, lengths,
                                        Wx1, b1, X, cnt);
  rnn_kernel<<<BATCH, 512, 0, stream>>>(X, Wh1, lengths, h1, nullptr);
  xprep_kernel<<<256, 256, 0, stream>>>(h1, Wx2, b2, X);
  // layer 2: writes f32 h2out AND f16 h2h (cast fused)
  rnn_kernel<<<BATCH, 512, 0, stream>>>(X, Wh2, lengths, h2out, h2h);

  dim3 gg(32, NCB);
  // pass 1: partials + in-kernel last-block combine -> Mrow/Inv
  gemm_kernel<0><<<gg, 256, 0, stream>>>(h2h, embh, nullptr, PM, PL,
                                         Mrow, Inv, lengths, cnt);
  // pass 2: recompute + fused exp/scale/mask, nontemporal probs stores
  gemm_kernel<1><<<gg, 256, 0, stream>>>(h2h, embh, probs, nullptr, nullptr,
                                         Mrow, Inv, lengths, nullptr);
}

// Round 6
// 1089.708 us; speedup vs baseline: 1.2959x; 1.2959x over previous
//
#include <hip/hip_runtime.h>
#include <hip/hip_bf16.h>

#define VOCAB 32000
#define HID   256
#define BATCH 32
#define SEQ   128
#define MROWS (BATCH * SEQ)  // 4096
#define NCB   250            // VOCAB / 128 column blocks

typedef _Float16 f16;
typedef _Float16 f16x4 __attribute__((ext_vector_type(4)));
typedef _Float16 f16x8 __attribute__((ext_vector_type(8)));
typedef float    f32x4 __attribute__((ext_vector_type(4)));

#define GLOAD_LDS16(gptr, lptr)                                                       \
  __builtin_amdgcn_global_load_lds(                                                   \
      (const __attribute__((address_space(1))) unsigned int*)(gptr),                  \
      (__attribute__((address_space(3))) unsigned int*)(lptr), 16, 0, 0)

// ---------------------------------------------------------------------------
// 1) prep: blocks [0,8000): emb fp32->fp16 cast; blocks [8000,8256):
//    X1 = (masked emb-gather) @ Wx1^T + b1 (16-row tiles).
//    NOTE (R5 lesson): NO device-scope fences/atomics anywhere on the hot
//    path — an agent-scope fence forces a per-block L2 writeback on gfx950
//    (non-coherent per-XCD L2s) and cost +356us across 8000 blocks.
// ---------------------------------------------------------------------------
__global__ __launch_bounds__(256) void prep_kernel(
    const float* __restrict__ emb, f16* __restrict__ embh,
    const int* __restrict__ tokens, const int* __restrict__ lengths,
    const float* __restrict__ W, const float* __restrict__ bias,
    float* __restrict__ Out) {
  const int blk = blockIdx.x;
  const int tid = threadIdx.x;
  if (blk < 8000) {  // cast: 8000*256 float4 = VOCAB*HID/4 exactly
    int idx = blk * 256 + tid;
    float4 v = ((const float4*)emb)[idx];
    f16x4 o = {(f16)v.x, (f16)v.y, (f16)v.z, (f16)v.w};
    ((f16x4*)embh)[idx] = o;
    return;
  }
  __shared__ float sIn[16 * 256];
  const int rb = (blk - 8000) * 16;
  float4* s4 = (float4*)sIn;
#pragma unroll
  for (int q = 0; q < 4; ++q) {
    int f = tid + q * 256;  // float4 index within 16x256 tile
    int row = f >> 6;       // 0..15
    int c4 = f & 63;
    int gr = rb + row;      // global row = b*SEQ + t
    int bb = gr >> 7, t = gr & 127;
    float4 v = make_float4(0.f, 0.f, 0.f, 0.f);
    if (t < lengths[bb]) {
      int tok = tokens[gr];
      v = ((const float4*)(emb + (size_t)tok * 256))[c4];
    }
    s4[f] = v;
  }
  __syncthreads();
  const int i = tid;
  float acc[16];
#pragma unroll
  for (int r = 0; r < 16; ++r) acc[r] = 0.f;
  const float4* w4 = (const float4*)(W + (size_t)i * 256);
#pragma unroll 4
  for (int j = 0; j < 64; ++j) {
    float4 wv = w4[j];
#pragma unroll
    for (int r = 0; r < 16; ++r) {
      float4 sv = ((const float4*)(sIn + r * 256))[j];
      acc[r] += sv.x * wv.x + sv.y * wv.y + sv.z * wv.z + sv.w * wv.w;
    }
  }
  float bi = bias[i];
#pragma unroll
  for (int r = 0; r < 16; ++r) Out[(size_t)(rb + r) * 256 + i] = acc[r] + bi;
}

// ---------------------------------------------------------------------------
// 2) X = In @ W^T + bias  (layer-2 input prep, linear In)
// ---------------------------------------------------------------------------
__global__ __launch_bounds__(256) void xprep_kernel(
    const float* __restrict__ In, const float* __restrict__ W,
    const float* __restrict__ bias, float* __restrict__ Out) {
  __shared__ float sIn[16 * 256];
  int tid = threadIdx.x;
  int rb = blockIdx.x * 16;
  const float4* g = (const float4*)(In + (size_t)rb * 256);
  float4* s4 = (float4*)sIn;
#pragma unroll
  for (int q = 0; q < 4; ++q) s4[tid + q * 256] = g[tid + q * 256];
  __syncthreads();
  int i = tid;
  float acc[16];
#pragma unroll
  for (int r = 0; r < 16; ++r) acc[r] = 0.f;
  const float4* w4 = (const float4*)(W + (size_t)i * 256);
#pragma unroll 4
  for (int j = 0; j < 64; ++j) {
    float4 wv = w4[j];
#pragma unroll
    for (int r = 0; r < 16; ++r) {
      float4 sv = ((const float4*)(sIn + r * 256))[j];
      acc[r] += sv.x * wv.x + sv.y * wv.y + sv.z * wv.z + sv.w * wv.w;
    }
  }
  float bi = bias[i];
#pragma unroll
  for (int r = 0; r < 16; ++r) Out[(size_t)(rb + r) * 256 + i] = acc[r] + bi;
}

// ---------------------------------------------------------------------------
// 3) recurrence: h_t = tanh(X_t + h_{t-1} @ Wh^T); wave-level K-split,
//    one barrier per step, fast tanh, optional f16 mirror (h2 cast fused).
// ---------------------------------------------------------------------------
__global__ __launch_bounds__(512) void rnn_kernel(
    const float* __restrict__ X, const float* __restrict__ Wh,
    const int* __restrict__ lengths, float* __restrict__ Hout,
    f16* __restrict__ H16) {
  int b = blockIdx.x;
  int tid = threadIdx.x;
  int wave = tid >> 6;
  int lane = tid & 63;
  int o = wave * 32 + (lane & 31);  // output index this lane serves
  int kh = lane >> 5;               // K-half (0/1)
  float w[128];
  {
    const float4* wr = (const float4*)(Wh + (size_t)o * 256 + kh * 128);
#pragma unroll
    for (int q = 0; q < 32; ++q) {
      float4 v = wr[q];
      w[4 * q + 0] = v.x; w[4 * q + 1] = v.y;
      w[4 * q + 2] = v.z; w[4 * q + 3] = v.w;
    }
  }
  __shared__ float sh[2][256];
  if (tid < 256) sh[0][tid] = 0.f;
  int len = lengths[b];
  const float* Xb = X + (size_t)b * SEQ * HID;
  float* Hb = Hout + (size_t)b * SEQ * HID;
  f16* H16b = H16 + (size_t)b * SEQ * HID;  // only deref'd if H16 != nullptr
  __syncthreads();
  float xnext = (kh == 0) ? Xb[o] : 0.f;
  for (int t = 0; t < SEQ; ++t) {
    const int cur = t & 1;
    float a0 = 0.f, a1 = 0.f, a2 = 0.f, a3 = 0.f;
    const float4* hp = (const float4*)(sh[cur] + kh * 128);
#pragma unroll
    for (int q = 0; q < 32; ++q) {
      float4 hv = hp[q];
      a0 += hv.x * w[4 * q + 0];
      a1 += hv.y * w[4 * q + 1];
      a2 += hv.z * w[4 * q + 2];
      a3 += hv.w * w[4 * q + 3];
    }
    float acc = (a0 + a1) + (a2 + a3);
    acc += __shfl_xor(acc, 32, 64);  // combine the two K-halves
    if (kh == 0) {
      float z = xnext + acc;
      float e = __expf(2.f * z);           // fast tanh: 1 - 2/(e^{2z}+1)
      float h = 1.f - 2.f / (e + 1.f);
      float hm = (t < len) ? h : 0.f;
      Hb[(size_t)t * HID + o] = hm;        // masked output
      if (H16) H16b[(size_t)t * HID + o] = (f16)hm;
      sh[cur ^ 1][o] = h;                  // unmasked carry
      if (t + 1 < SEQ) xnext = Xb[(size_t)(t + 1) * HID + o];
    }
    __syncthreads();
  }
}

// ---------------------------------------------------------------------------
// 4) Two-pass fused GEMM+softmax, double-buffered prefetch K-loop.
//    Pass 1: per-block online-softmax partials -> PM/PL (no logits write).
//    Pass 2: recompute + exp/scale/mask, nontemporal probs stores.
//    Combine is a separate 7us dispatch (R5: in-kernel fence combine = -356us).
// ---------------------------------------------------------------------------
template <int WRITE_PROBS>
__global__ __launch_bounds__(256) void gemm_kernel(
    const f16* __restrict__ A,   // [4096][256] masked h2
    const f16* __restrict__ Bm,  // [32000][256] emb
    float* __restrict__ C,       // [4096][32000] probs (pass 2 only)
    float* __restrict__ PM,      // [4096][250] partial row max (pass 1)
    float* __restrict__ PL,      // [4096][250] partial sum exp (pass 1)
    const float* __restrict__ Mrow,  // [4096] row max (pass 2)
    const float* __restrict__ Inv,   // [4096] 1/denominator (pass 2)
    const int* __restrict__ lengths) {
  __shared__ __align__(16) f16 sAbuf[2][128 * 64];  // 32 KB
  __shared__ __align__(16) f16 sBbuf[2][128 * 64];  // 32 KB  (total = 64 KB)
  const int tid = threadIdx.x;
  const int wave = tid >> 6;
  const int lane = tid & 63;

  // XCD-chunked remap (8000 blocks, 1000 per XCD; round-robin dispatch)
  const int flat = blockIdx.x + 32 * blockIdx.y;
  const int work = (flat & 7) * 1000 + (flat >> 3);
  const int bx = work & 31;   // row-block == batch element
  const int by = work >> 5;   // col-block
  const int row0 = bx * 128;
  const int col0 = by * 128;

  const int len = lengths[bx];         // block-uniform
  const int lenc = (len + 15) & ~15;   // rows needed, frag-rounded

  f32x4 acc[4][4];
#pragma unroll
  for (int a = 0; a < 4; ++a)
#pragma unroll
    for (int b = 0; b < 4; ++b) acc[a][b] = (f32x4){0.f, 0.f, 0.f, 0.f};

  const int lr = lane >> 3;  // row within 8-row group
  const int ls = lane & 7;   // LDS 16B slot within row
  const int wm = wave & 1, wn = wave >> 1;

#define STAGE(buf, koo)                                                        \
  {                                                                            \
    _Pragma("unroll") for (int ii = 0; ii < 4; ++ii) {                         \
      int ar = wave * 32 + ii * 8;                                             \
      int r = ar + lr;                                                         \
      int c = ls ^ (r & 7);                                                    \
      if (ar < lenc) {                                                         \
        const f16* ga = A + (size_t)(row0 + r) * 256 + (koo) * 64 + c * 8;     \
        GLOAD_LDS16(ga, sAbuf[buf] + ar * 64);                                 \
      }                                                                        \
      const f16* gb = Bm + (size_t)(col0 + r) * 256 + (koo) * 64 + c * 8;      \
      GLOAD_LDS16(gb, sBbuf[buf] + ar * 64);                                   \
    }                                                                          \
  }

  STAGE(0, 0);
  __syncthreads();  // prologue drain (implicit vmcnt(0))

#pragma unroll
  for (int ko = 0; ko < 4; ++ko) {
    const int cur = ko & 1;
    if (ko < 3) STAGE(cur ^ 1, ko + 1);  // prefetch overlaps compute below
#pragma unroll
    for (int kk = 0; kk < 2; ++kk) {
      const int cA = kk * 4 + (lane >> 4);
      f16x8 bf[4];
#pragma unroll
      for (int f = 0; f < 4; ++f) {
        int n = wn * 64 + f * 16 + (lane & 15);
        bf[f] = *(const f16x8*)(sBbuf[cur] + n * 64 + (cA ^ (n & 7)) * 8);
      }
#pragma unroll
      for (int fm = 0; fm < 4; ++fm) {
        const int g = fm * 2 + wm;        // interleaved row-frag index
        if (g * 16 < len) {               // wave-uniform guard
          int m = g * 16 + (lane & 15);
          f16x8 af = *(const f16x8*)(sAbuf[cur] + m * 64 + (cA ^ (m & 7)) * 8);
#pragma unroll
          for (int fn = 0; fn < 4; ++fn)
            acc[fm][fn] = __builtin_amdgcn_mfma_f32_16x16x32_f16(
                af, bf[fn], acc[fm][fn], 0, 0, 0);
        }
      }
    }
    __syncthreads();  // next buffer ready + old buffer readers done
  }
#undef STAGE

  const int lq = lane >> 4;
  const int lc = lane & 15;

  if (WRITE_PROBS) {
    // --- pass 2: probs = exp(acc - m) * inv, masked rows -> 0 ---
    // C/D layout: col=lane&15, row=(lane>>4)*4+reg.  Nontemporal stores.
    float* sM = (float*)sAbuf;  // staging buffers dead after final barrier
    float* sI = sM + 128;
    if (tid < 128) {
      sM[tid] = Mrow[row0 + tid];
      sI[tid] = Inv[row0 + tid];
    }
    __syncthreads();
#pragma unroll
    for (int fm = 0; fm < 4; ++fm)
#pragma unroll
      for (int fn = 0; fn < 4; ++fn)
#pragma unroll
        for (int rr = 0; rr < 4; ++rr) {
          int t = (fm * 2 + wm) * 16 + lq * 4 + rr;  // t within batch
          int col = col0 + wn * 64 + fn * 16 + lc;
          float v =
              (t < len) ? __expf(acc[fm][fn][rr] - sM[t]) * sI[t] : 0.f;
          __builtin_nontemporal_store(v, &C[(size_t)(row0 + t) * VOCAB + col]);
        }
  } else {
    // --- pass 1: per-block online-softmax partials; reuse staging LDS ---
    float* rm = (float*)sAbuf;     // [2][128]  per-wn per-row max
    float* rs = rm + 256;          // [2][128]  per-wn per-row sum exp
#pragma unroll
    for (int fm = 0; fm < 4; ++fm) {
      const int g = fm * 2 + wm;
      const bool active = (g * 16 < len);  // wave-uniform
#pragma unroll
      for (int rr = 0; rr < 4; ++rr) {
        int r = g * 16 + lq * 4 + rr;
        if (active) {
          float mx = fmaxf(fmaxf(acc[fm][0][rr], acc[fm][1][rr]),
                           fmaxf(acc[fm][2][rr], acc[fm][3][rr]));
#pragma unroll
          for (int off = 1; off < 16; off <<= 1)
            mx = fmaxf(mx, __shfl_xor(mx, off, 64));
          float sum = __expf(acc[fm][0][rr] - mx) +
                      __expf(acc[fm][1][rr] - mx) +
                      __expf(acc[fm][2][rr] - mx) +
                      __expf(acc[fm][3][rr] - mx);
#pragma unroll
          for (int off = 1; off < 16; off <<= 1)
            sum += __shfl_xor(sum, off, 64);
          if (lc == 0) {
            rm[wn * 128 + r] = mx;
            rs[wn * 128 + r] = sum;
          }
        } else if (lc == 0) {  // padded rows: benign partials (unused)
          rm[wn * 128 + r] = 0.f;
          rs[wn * 128 + r] = 0.f;
        }
      }
    }
    __syncthreads();
    if (tid < 128) {
      float m0 = rm[tid], m1 = rm[128 + tid];
      float M = fmaxf(m0, m1);
      float L = rs[tid] * __expf(m0 - M) + rs[128 + tid] * __expf(m1 - M);
      PM[(size_t)(row0 + tid) * NCB + by] = M;
      PL[(size_t)(row0 + tid) * NCB + by] = L;
    }
  }
}

// ---------------------------------------------------------------------------
// 5) combine 250 partials per row -> m[row], inv[row]. One wave per row.
// ---------------------------------------------------------------------------
__global__ __launch_bounds__(256) void combine_kernel(
    const float* __restrict__ PM, const float* __restrict__ PL,
    float* __restrict__ Mrow, float* __restrict__ Inv) {
  int row = blockIdx.x * 4 + (threadIdx.x >> 6);
  int lane = threadIdx.x & 63;
  const float* pm = PM + (size_t)row * NCB;
  const float* pl = PL + (size_t)row * NCB;
  float M = -3.4e38f;
  for (int i = lane; i < NCB; i += 64) M = fmaxf(M, pm[i]);
#pragma unroll
  for (int off = 1; off < 64; off <<= 1) M = fmaxf(M, __shfl_xor(M, off, 64));
  float L = 0.f;
  for (int i = lane; i < NCB; i += 64) L += pl[i] * __expf(pm[i] - M);
#pragma unroll
  for (int off = 1; off < 64; off <<= 1) L += __shfl_xor(L, off, 64);
  if (lane == 0) {
    Mrow[row] = M;
    Inv[row] = 1.f / L;
  }
}

// ---------------------------------------------------------------------------
extern "C" void kernel_launch(void* const* d_in, const int* in_sizes, int n_in,
                              void* d_out, int out_size, void* d_ws,
                              size_t ws_size, hipStream_t stream) {
  const int* tokens = (const int*)d_in[0];
  const int* lengths = (const int*)d_in[1];
  const float* emb = (const float*)d_in[2];
  const float* Wx1 = (const float*)d_in[3];
  const float* Wh1 = (const float*)d_in[4];
  const float* b1 = (const float*)d_in[5];
  const float* Wx2 = (const float*)d_in[6];
  const float* Wh2 = (const float*)d_in[7];
  const float* b2 = (const float*)d_in[8];

  float* probs = (float*)d_out;
  float* h2out = probs + (size_t)MROWS * VOCAB;  // [4096][256] masked h2

  float* ws = (float*)d_ws;
  float* X = ws + 1048576;                     // 1,048,576 f (reused layer 2)
  float* h1 = ws + 2097152;                    // 1,048,576 f
  f16* embh = (f16*)(ws + 3145728);            // 8,192,000 halfs = 4,096,000 f
  f16* h2h = (f16*)(ws + 3145728 + 4096000);   // 1,048,576 halfs = 524,288 f
  float* PM = ws + 7766016;                    // 1,024,000 f
  float* PL = ws + 8790016;                    // 1,024,000 f
  float* Mrow = ws + 9814016;                  // 4096 f
  float* Inv = ws + 9818112;                   // 4096 f

  // 1: emb cast (blocks 0..7999) + gather-xprep1 (8000..8255)
  prep_kernel<<<8256, 256, 0, stream>>>(emb, embh, tokens, lengths,
                                        Wx1, b1, X);
  rnn_kernel<<<BATCH, 512, 0, stream>>>(X, Wh1, lengths, h1, nullptr);
  xprep_kernel<<<256, 256, 0, stream>>>(h1, Wx2, b2, X);
  // layer 2: writes f32 h2out AND f16 h2h (cast fused)
  rnn_kernel<<<BATCH, 512, 0, stream>>>(X, Wh2, lengths, h2out, h2h);

  dim3 gg(32, NCB);
  // pass 1: partials only (no 524MB logits write), length-skipped
  gemm_kernel<0><<<gg, 256, 0, stream>>>(h2h, embh, nullptr, PM, PL,
                                         nullptr, nullptr, lengths);
  combine_kernel<<<MROWS / 4, 256, 0, stream>>>(PM, PL, Mrow, Inv);
  // pass 2: recompute + fused exp/scale/mask, nontemporal probs stores
  gemm_kernel<1><<<gg, 256, 0, stream>>>(h2h, embh, probs, nullptr, nullptr,
                                         Mrow, Inv, lengths);
}

// Round 7
// 1041.488 us; speedup vs baseline: 1.3559x; 1.0463x over previous
//
#include <hip/hip_runtime.h>
#include <hip/hip_bf16.h>

#define VOCAB 32000
#define HID   256
#define BATCH 32
#define SEQ   128
#define MROWS (BATCH * SEQ)  // 4096
#define NCB   250            // VOCAB / 128 column blocks

typedef _Float16 f16;
typedef _Float16 f16x4 __attribute__((ext_vector_type(4)));
typedef _Float16 f16x8 __attribute__((ext_vector_type(8)));
typedef float    f32x4 __attribute__((ext_vector_type(4)));

#define GLOAD_LDS16(gptr, lptr)                                                       \
  __builtin_amdgcn_global_load_lds(                                                   \
      (const __attribute__((address_space(1))) unsigned int*)(gptr),                  \
      (__attribute__((address_space(3))) unsigned int*)(lptr), 16, 0, 0)

// ---------------------------------------------------------------------------
// 1) X = In @ W^T + bias.  GATHER=1: In rows come from emb[tokens[row]]
//    masked by length (embed fused into staging); GATHER=0: linear In.
//    (R4-proven version; R6's 8256-block prep fusion regressed -34us.)
// ---------------------------------------------------------------------------
template <int GATHER>
__global__ __launch_bounds__(256) void xprep_kernel(
    const float* __restrict__ In, const int* __restrict__ tokens,
    const int* __restrict__ lengths, const float* __restrict__ emb,
    const float* __restrict__ W, const float* __restrict__ bias,
    float* __restrict__ Out) {
  __shared__ float sIn[16 * 256];
  int tid = threadIdx.x;
  int rb = blockIdx.x * 16;
  float4* s4 = (float4*)sIn;
#pragma unroll
  for (int q = 0; q < 4; ++q) {
    int f = tid + q * 256;  // float4 index within 16x256 tile
    float4 v;
    if (GATHER) {
      int row = f >> 6;     // 0..15
      int c4 = f & 63;
      int gr = rb + row;    // global row = b*SEQ + t
      int bb = gr >> 7, t = gr & 127;
      if (t < lengths[bb]) {
        int tok = tokens[gr];
        v = ((const float4*)(emb + (size_t)tok * 256))[c4];
      } else {
        v = make_float4(0.f, 0.f, 0.f, 0.f);
      }
    } else {
      v = ((const float4*)(In + (size_t)rb * 256))[f];
    }
    s4[f] = v;
  }
  __syncthreads();
  int i = tid;
  float acc[16];
#pragma unroll
  for (int r = 0; r < 16; ++r) acc[r] = 0.f;
  const float4* w4 = (const float4*)(W + (size_t)i * 256);
#pragma unroll 4
  for (int j = 0; j < 64; ++j) {
    float4 wv = w4[j];
#pragma unroll
    for (int r = 0; r < 16; ++r) {
      float4 sv = ((const float4*)(sIn + r * 256))[j];
      acc[r] += sv.x * wv.x + sv.y * wv.y + sv.z * wv.z + sv.w * wv.w;
    }
  }
  float bi = bias[i];
#pragma unroll
  for (int r = 0; r < 16; ++r) Out[(size_t)(rb + r) * 256 + i] = acc[r] + bi;
}

// ---------------------------------------------------------------------------
// 2) rnn layer 1 + emb cast merged.  Blocks [0,32): recurrence for batch b
//    (latency-bound, leaves 224 CUs idle).  Blocks [32, 32+4000): emb
//    fp32->fp16 cast rides on the idle CUs (independent work, no sync).
//    RNN: wave-level K-split, one barrier/step, fast tanh (R4-proven).
// ---------------------------------------------------------------------------
__global__ __launch_bounds__(512) void rnn1_cast_kernel(
    const float* __restrict__ X, const float* __restrict__ Wh,
    const int* __restrict__ lengths, float* __restrict__ Hout,
    const float* __restrict__ emb, f16* __restrict__ embh) {
  if (blockIdx.x >= BATCH) {
    // cast path: 4000 blocks x 512 threads = 2,048,000 float4 = VOCAB*HID/4
    int idx = (blockIdx.x - BATCH) * 512 + threadIdx.x;
    float4 v = ((const float4*)emb)[idx];
    f16x4 o = {(f16)v.x, (f16)v.y, (f16)v.z, (f16)v.w};
    ((f16x4*)embh)[idx] = o;
    return;
  }
  int b = blockIdx.x;
  int tid = threadIdx.x;
  int wave = tid >> 6;
  int lane = tid & 63;
  int o = wave * 32 + (lane & 31);  // output index this lane serves
  int kh = lane >> 5;               // K-half (0/1)
  float w[128];
  {
    const float4* wr = (const float4*)(Wh + (size_t)o * 256 + kh * 128);
#pragma unroll
    for (int q = 0; q < 32; ++q) {
      float4 v = wr[q];
      w[4 * q + 0] = v.x; w[4 * q + 1] = v.y;
      w[4 * q + 2] = v.z; w[4 * q + 3] = v.w;
    }
  }
  __shared__ float sh[2][256];
  if (tid < 256) sh[0][tid] = 0.f;
  int len = lengths[b];
  const float* Xb = X + (size_t)b * SEQ * HID;
  float* Hb = Hout + (size_t)b * SEQ * HID;
  __syncthreads();
  float xnext = (kh == 0) ? Xb[o] : 0.f;
  for (int t = 0; t < SEQ; ++t) {
    const int cur = t & 1;
    float a0 = 0.f, a1 = 0.f, a2 = 0.f, a3 = 0.f;
    const float4* hp = (const float4*)(sh[cur] + kh * 128);
#pragma unroll
    for (int q = 0; q < 32; ++q) {
      float4 hv = hp[q];
      a0 += hv.x * w[4 * q + 0];
      a1 += hv.y * w[4 * q + 1];
      a2 += hv.z * w[4 * q + 2];
      a3 += hv.w * w[4 * q + 3];
    }
    float acc = (a0 + a1) + (a2 + a3);
    acc += __shfl_xor(acc, 32, 64);  // combine the two K-halves
    if (kh == 0) {
      float z = xnext + acc;
      float e = __expf(2.f * z);           // fast tanh: 1 - 2/(e^{2z}+1)
      float h = 1.f - 2.f / (e + 1.f);
      Hb[(size_t)t * HID + o] = (t < len) ? h : 0.f;  // masked output
      sh[cur ^ 1][o] = h;                             // unmasked carry
      if (t + 1 < SEQ) xnext = Xb[(size_t)(t + 1) * HID + o];
    }
    __syncthreads();
  }
}

// ---------------------------------------------------------------------------
// 3) rnn layer 2: same recurrence, plus f16 mirror of the masked output
//    (fuses the h2 cast for the gemm A-operand).
// ---------------------------------------------------------------------------
__global__ __launch_bounds__(512) void rnn_kernel(
    const float* __restrict__ X, const float* __restrict__ Wh,
    const int* __restrict__ lengths, float* __restrict__ Hout,
    f16* __restrict__ H16) {
  int b = blockIdx.x;
  int tid = threadIdx.x;
  int wave = tid >> 6;
  int lane = tid & 63;
  int o = wave * 32 + (lane & 31);
  int kh = lane >> 5;
  float w[128];
  {
    const float4* wr = (const float4*)(Wh + (size_t)o * 256 + kh * 128);
#pragma unroll
    for (int q = 0; q < 32; ++q) {
      float4 v = wr[q];
      w[4 * q + 0] = v.x; w[4 * q + 1] = v.y;
      w[4 * q + 2] = v.z; w[4 * q + 3] = v.w;
    }
  }
  __shared__ float sh[2][256];
  if (tid < 256) sh[0][tid] = 0.f;
  int len = lengths[b];
  const float* Xb = X + (size_t)b * SEQ * HID;
  float* Hb = Hout + (size_t)b * SEQ * HID;
  f16* H16b = H16 + (size_t)b * SEQ * HID;
  __syncthreads();
  float xnext = (kh == 0) ? Xb[o] : 0.f;
  for (int t = 0; t < SEQ; ++t) {
    const int cur = t & 1;
    float a0 = 0.f, a1 = 0.f, a2 = 0.f, a3 = 0.f;
    const float4* hp = (const float4*)(sh[cur] + kh * 128);
#pragma unroll
    for (int q = 0; q < 32; ++q) {
      float4 hv = hp[q];
      a0 += hv.x * w[4 * q + 0];
      a1 += hv.y * w[4 * q + 1];
      a2 += hv.z * w[4 * q + 2];
      a3 += hv.w * w[4 * q + 3];
    }
    float acc = (a0 + a1) + (a2 + a3);
    acc += __shfl_xor(acc, 32, 64);
    if (kh == 0) {
      float z = xnext + acc;
      float e = __expf(2.f * z);
      float h = 1.f - 2.f / (e + 1.f);
      float hm = (t < len) ? h : 0.f;
      Hb[(size_t)t * HID + o] = hm;
      H16b[(size_t)t * HID + o] = (f16)hm;
      sh[cur ^ 1][o] = h;
      if (t + 1 < SEQ) xnext = Xb[(size_t)(t + 1) * HID + o];
    }
    __syncthreads();
  }
}

// ---------------------------------------------------------------------------
// 4) Two-pass fused GEMM+softmax, double-buffered prefetch K-loop.
//    Pass 1: per-block online-softmax partials -> PM/PL (no logits write).
//    Pass 2: recompute + exp/scale/mask, nontemporal probs stores.
//    Combine stays a separate dispatch (R5: per-block device fences = -356us).
// ---------------------------------------------------------------------------
template <int WRITE_PROBS>
__global__ __launch_bounds__(256) void gemm_kernel(
    const f16* __restrict__ A,   // [4096][256] masked h2
    const f16* __restrict__ Bm,  // [32000][256] emb
    float* __restrict__ C,       // [4096][32000] probs (pass 2 only)
    float* __restrict__ PM,      // [4096][250] partial row max (pass 1)
    float* __restrict__ PL,      // [4096][250] partial sum exp (pass 1)
    const float* __restrict__ Mrow,  // [4096] row max (pass 2)
    const float* __restrict__ Inv,   // [4096] 1/denominator (pass 2)
    const int* __restrict__ lengths) {
  __shared__ __align__(16) f16 sAbuf[2][128 * 64];  // 32 KB
  __shared__ __align__(16) f16 sBbuf[2][128 * 64];  // 32 KB  (total = 64 KB)
  const int tid = threadIdx.x;
  const int wave = tid >> 6;
  const int lane = tid & 63;

  // XCD-chunked remap (8000 blocks, 1000 per XCD; round-robin dispatch)
  const int flat = blockIdx.x + 32 * blockIdx.y;
  const int work = (flat & 7) * 1000 + (flat >> 3);
  const int bx = work & 31;   // row-block == batch element
  const int by = work >> 5;   // col-block
  const int row0 = bx * 128;
  const int col0 = by * 128;

  const int len = lengths[bx];         // block-uniform
  const int lenc = (len + 15) & ~15;   // rows needed, frag-rounded

  f32x4 acc[4][4];
#pragma unroll
  for (int a = 0; a < 4; ++a)
#pragma unroll
    for (int b = 0; b < 4; ++b) acc[a][b] = (f32x4){0.f, 0.f, 0.f, 0.f};

  const int lr = lane >> 3;  // row within 8-row group
  const int ls = lane & 7;   // LDS 16B slot within row
  const int wm = wave & 1, wn = wave >> 1;

#define STAGE(buf, koo)                                                        \
  {                                                                            \
    _Pragma("unroll") for (int ii = 0; ii < 4; ++ii) {                         \
      int ar = wave * 32 + ii * 8;                                             \
      int r = ar + lr;                                                         \
      int c = ls ^ (r & 7);                                                    \
      if (ar < lenc) {                                                         \
        const f16* ga = A + (size_t)(row0 + r) * 256 + (koo) * 64 + c * 8;     \
        GLOAD_LDS16(ga, sAbuf[buf] + ar * 64);                                 \
      }                                                                        \
      const f16* gb = Bm + (size_t)(col0 + r) * 256 + (koo) * 64 + c * 8;      \
      GLOAD_LDS16(gb, sBbuf[buf] + ar * 64);                                   \
    }                                                                          \
  }

  STAGE(0, 0);
  __syncthreads();  // prologue drain (implicit vmcnt(0))

#pragma unroll
  for (int ko = 0; ko < 4; ++ko) {
    const int cur = ko & 1;
    if (ko < 3) STAGE(cur ^ 1, ko + 1);  // prefetch overlaps compute below
#pragma unroll
    for (int kk = 0; kk < 2; ++kk) {
      const int cA = kk * 4 + (lane >> 4);
      f16x8 bf[4];
#pragma unroll
      for (int f = 0; f < 4; ++f) {
        int n = wn * 64 + f * 16 + (lane & 15);
        bf[f] = *(const f16x8*)(sBbuf[cur] + n * 64 + (cA ^ (n & 7)) * 8);
      }
#pragma unroll
      for (int fm = 0; fm < 4; ++fm) {
        const int g = fm * 2 + wm;        // interleaved row-frag index
        if (g * 16 < len) {               // wave-uniform guard
          int m = g * 16 + (lane & 15);
          f16x8 af = *(const f16x8*)(sAbuf[cur] + m * 64 + (cA ^ (m & 7)) * 8);
#pragma unroll
          for (int fn = 0; fn < 4; ++fn)
            acc[fm][fn] = __builtin_amdgcn_mfma_f32_16x16x32_f16(
                af, bf[fn], acc[fm][fn], 0, 0, 0);
        }
      }
    }
    __syncthreads();  // next buffer ready + old buffer readers done
  }
#undef STAGE

  const int lq = lane >> 4;
  const int lc = lane & 15;

  if (WRITE_PROBS) {
    // --- pass 2: probs = exp(acc - m) * inv, masked rows -> 0 ---
    // C/D layout: col=lane&15, row=(lane>>4)*4+reg.  Nontemporal stores.
    float* sM = (float*)sAbuf;  // staging buffers dead after final barrier
    float* sI = sM + 128;
    if (tid < 128) {
      sM[tid] = Mrow[row0 + tid];
      sI[tid] = Inv[row0 + tid];
    }
    __syncthreads();
#pragma unroll
    for (int fm = 0; fm < 4; ++fm)
#pragma unroll
      for (int fn = 0; fn < 4; ++fn)
#pragma unroll
        for (int rr = 0; rr < 4; ++rr) {
          int t = (fm * 2 + wm) * 16 + lq * 4 + rr;  // t within batch
          int col = col0 + wn * 64 + fn * 16 + lc;
          float v =
              (t < len) ? __expf(acc[fm][fn][rr] - sM[t]) * sI[t] : 0.f;
          __builtin_nontemporal_store(v, &C[(size_t)(row0 + t) * VOCAB + col]);
        }
  } else {
    // --- pass 1: per-block online-softmax partials; reuse staging LDS ---
    float* rm = (float*)sAbuf;     // [2][128]  per-wn per-row max
    float* rs = rm + 256;          // [2][128]  per-wn per-row sum exp
#pragma unroll
    for (int fm = 0; fm < 4; ++fm) {
      const int g = fm * 2 + wm;
      const bool active = (g * 16 < len);  // wave-uniform
#pragma unroll
      for (int rr = 0; rr < 4; ++rr) {
        int r = g * 16 + lq * 4 + rr;
        if (active) {
          float mx = fmaxf(fmaxf(acc[fm][0][rr], acc[fm][1][rr]),
                           fmaxf(acc[fm][2][rr], acc[fm][3][rr]));
#pragma unroll
          for (int off = 1; off < 16; off <<= 1)
            mx = fmaxf(mx, __shfl_xor(mx, off, 64));
          float sum = __expf(acc[fm][0][rr] - mx) +
                      __expf(acc[fm][1][rr] - mx) +
                      __expf(acc[fm][2][rr] - mx) +
                      __expf(acc[fm][3][rr] - mx);
#pragma unroll
          for (int off = 1; off < 16; off <<= 1)
            sum += __shfl_xor(sum, off, 64);
          if (lc == 0) {
            rm[wn * 128 + r] = mx;
            rs[wn * 128 + r] = sum;
          }
        } else if (lc == 0) {  // padded rows: benign partials (unused)
          rm[wn * 128 + r] = 0.f;
          rs[wn * 128 + r] = 0.f;
        }
      }
    }
    __syncthreads();
    if (tid < 128) {
      float m0 = rm[tid], m1 = rm[128 + tid];
      float M = fmaxf(m0, m1);
      float L = rs[tid] * __expf(m0 - M) + rs[128 + tid] * __expf(m1 - M);
      PM[(size_t)(row0 + tid) * NCB + by] = M;
      PL[(size_t)(row0 + tid) * NCB + by] = L;
    }
  }
}

// ---------------------------------------------------------------------------
// 5) combine 250 partials per row -> m[row], inv[row]. One wave per row.
// ---------------------------------------------------------------------------
__global__ __launch_bounds__(256) void combine_kernel(
    const float* __restrict__ PM, const float* __restrict__ PL,
    float* __restrict__ Mrow, float* __restrict__ Inv) {
  int row = blockIdx.x * 4 + (threadIdx.x >> 6);
  int lane = threadIdx.x & 63;
  const float* pm = PM + (size_t)row * NCB;
  const float* pl = PL + (size_t)row * NCB;
  float M = -3.4e38f;
  for (int i = lane; i < NCB; i += 64) M = fmaxf(M, pm[i]);
#pragma unroll
  for (int off = 1; off < 64; off <<= 1) M = fmaxf(M, __shfl_xor(M, off, 64));
  float L = 0.f;
  for (int i = lane; i < NCB; i += 64) L += pl[i] * __expf(pm[i] - M);
#pragma unroll
  for (int off = 1; off < 64; off <<= 1) L += __shfl_xor(L, off, 64);
  if (lane == 0) {
    Mrow[row] = M;
    Inv[row] = 1.f / L;
  }
}

// ---------------------------------------------------------------------------
extern "C" void kernel_launch(void* const* d_in, const int* in_sizes, int n_in,
                              void* d_out, int out_size, void* d_ws,
                              size_t ws_size, hipStream_t stream) {
  const int* tokens = (const int*)d_in[0];
  const int* lengths = (const int*)d_in[1];
  const float* emb = (const float*)d_in[2];
  const float* Wx1 = (const float*)d_in[3];
  const float* Wh1 = (const float*)d_in[4];
  const float* b1 = (const float*)d_in[5];
  const float* Wx2 = (const float*)d_in[6];
  const float* Wh2 = (const float*)d_in[7];
  const float* b2 = (const float*)d_in[8];

  float* probs = (float*)d_out;
  float* h2out = probs + (size_t)MROWS * VOCAB;  // [4096][256] masked h2

  float* ws = (float*)d_ws;
  float* X = ws + 1048576;                     // 1,048,576 f (reused layer 2)
  float* h1 = ws + 2097152;                    // 1,048,576 f
  f16* embh = (f16*)(ws + 3145728);            // 8,192,000 halfs = 4,096,000 f
  f16* h2h = (f16*)(ws + 3145728 + 4096000);   // 1,048,576 halfs = 524,288 f
  float* PM = ws + 7766016;                    // 1,024,000 f
  float* PL = ws + 8790016;                    // 1,024,000 f
  float* Mrow = ws + 9814016;                  // 4096 f
  float* Inv = ws + 9818112;                   // 4096 f

  // layer 1 input: X1 = masked-emb-gather @ Wx1^T + b1
  xprep_kernel<1><<<256, 256, 0, stream>>>(nullptr, tokens, lengths, emb,
                                           Wx1, b1, X);
  // rnn layer 1 (blocks 0-31) + emb f16 cast on the idle CUs (blocks 32+)
  rnn1_cast_kernel<<<BATCH + 4000, 512, 0, stream>>>(X, Wh1, lengths, h1,
                                                     emb, embh);
  xprep_kernel<0><<<256, 256, 0, stream>>>(h1, nullptr, nullptr, nullptr,
                                           Wx2, b2, X);
  // rnn layer 2: writes f32 h2out AND f16 h2h (cast fused)
  rnn_kernel<<<BATCH, 512, 0, stream>>>(X, Wh2, lengths, h2out, h2h);

  dim3 gg(32, NCB);
  // pass 1: partials only (no 524MB logits write), length-skipped
  gemm_kernel<0><<<gg, 256, 0, stream>>>(h2h, embh, nullptr, PM, PL,
                                         nullptr, nullptr, lengths);
  combine_kernel<<<MROWS / 4, 256, 0, stream>>>(PM, PL, Mrow, Inv);
  // pass 2: recompute + fused exp/scale/mask, nontemporal probs stores
  gemm_kernel<1><<<gg, 256, 0, stream>>>(h2h, embh, probs, nullptr, nullptr,
                                         Mrow, Inv, lengths);
}